// Round 8
// baseline (88.916 us; speedup 1.0000x reference)
//
#include <hip/hip_runtime.h>

#define NROWS  32768
#define DDIM   256
#define KCODES 1024

typedef _Float16 half8 __attribute__((ext_vector_type(8)));
typedef float floatx4 __attribute__((ext_vector_type(4)));

// ws layout: [0,4096) f32 cnorm[1024];
//            [4096, 4096+524288) fp16 E' chunk-major fragment-ready:
//   16B slot = (ct*8 + kc)*1024 + lq*256 + cr   holds fp16 of
//   cb[ct*256+cr][kc*32 + lq*8 .. +8)

// ---------------------------------------------------------------------------
// prep kernel: codebook f32 -> fp16 fragment layout + np-pairwise cnorm
// (validated R1-R7, unchanged)
// ---------------------------------------------------------------------------
__global__ void prep_kernel(const float* __restrict__ cb,
                            float* __restrict__ cnorm,
                            _Float16* __restrict__ ep) {
    int idx  = blockIdx.x * 512 + threadIdx.x;   // 64 x 512 = 32768
    int code = idx >> 5, kl = idx & 31;
    int dc = kl >> 2, lq = kl & 3;
    int ct = code >> 8, cr = code & 255;
    const float4* s = reinterpret_cast<const float4*>(cb + (size_t)code * DDIM + kl * 8);
    float4 a = s[0], b = s[1];
    half8 h;
    h[0] = (_Float16)a.x; h[1] = (_Float16)a.y; h[2] = (_Float16)a.z; h[3] = (_Float16)a.w;
    h[4] = (_Float16)b.x; h[5] = (_Float16)b.y; h[6] = (_Float16)b.z; h[7] = (_Float16)b.w;
    size_t slot = (size_t)(ct * 8 + dc) * 1024 + lq * 256 + cr;
    *reinterpret_cast<half8*>(ep + slot * 8) = h;

    if (threadIdx.x < 16) {
        int k = blockIdx.x * 16 + threadIdx.x;
        const float* p = cb + (size_t)k * DDIM;
        float halves[2];
        for (int hh = 0; hh < 2; ++hh) {
            const float* aa = p + hh * 128;
            float r[8];
#pragma unroll
            for (int j = 0; j < 8; ++j) r[j] = __fmul_rn(aa[j], aa[j]);
            for (int i = 8; i < 128; i += 8) {
#pragma unroll
                for (int j = 0; j < 8; ++j)
                    r[j] = __fadd_rn(r[j], __fmul_rn(aa[i + j], aa[i + j]));
            }
            halves[hh] = __fadd_rn(__fadd_rn(__fadd_rn(r[0], r[1]), __fadd_rn(r[2], r[3])),
                                   __fadd_rn(__fadd_rn(r[4], r[5]), __fadd_rn(r[6], r[7])));
        }
        cnorm[k] = __fadd_rn(halves[0], halves[1]);
    }
}

// numpy-pairwise ||x||^2 from a global row pointer (validated R2-R7)
__device__ __forceinline__ float xnorm_np_g(const float* __restrict__ p) {
    float halves[2];
    for (int h = 0; h < 2; ++h) {
        const float* a = p + h * 128;
        float r[8];
#pragma unroll
        for (int j = 0; j < 8; ++j) r[j] = __fmul_rn(a[j], a[j]);
        for (int i = 8; i < 128; i += 8) {
#pragma unroll
            for (int j = 0; j < 8; ++j)
                r[j] = __fadd_rn(r[j], __fmul_rn(a[i + j], a[i + j]));
        }
        halves[h] = __fadd_rn(__fadd_rn(__fadd_rn(r[0], r[1]), __fadd_rn(r[2], r[3])),
                              __fadd_rn(__fadd_rn(r[4], r[5]), __fadd_rn(r[6], r[7])));
    }
    return __fadd_rn(halves[0], halves[1]);
}

// ---------------------------------------------------------------------------
// main kernel: identical structure to R7 (64 rows x 64 codes wave-tile,
// 16 MFMA : 4 ds_read : 4 global per k-step) but with the occupancy window
// PINNED at 3 waves/EU via amdgpu_waves_per_eu(3,3) so the allocator gets a
// 170-VGPR budget and neither spills acc (R7 failure: min-only bound ->
// 6 waves/EU target -> 84 VGPR + 150 MB scratch traffic) nor rematerializes
// the prefetch ring (R5/R6 failure at 120-128 VGPR).
// ---------------------------------------------------------------------------
__global__ __launch_bounds__(256)
__attribute__((amdgpu_waves_per_eu(3, 3)))
void som_mfma_kernel(
    const float* __restrict__ x, const float* __restrict__ cb,
    const float* __restrict__ cnorm, const _Float16* __restrict__ ep,
    float* __restrict__ out)
{
    __shared__ __align__(16) char smem[32768];

    const int tid  = threadIdx.x;
    const int lane = tid & 63, w = tid >> 6;     // wave 0..3 = 256-code strip
    const int l15  = lane & 15, lq = lane >> 4;
    const int row0 = blockIdx.x * 64;

    // ---- stage X (64 rows) coalesced -> fp16 fragment layout in LDS ----
    {
        int row = tid >> 2, qd = tid & 3;
        const float4* src = reinterpret_cast<const float4*>(
            x + (size_t)(row0 + row) * DDIM + qd * 64);
        float4 f[16];
#pragma unroll
        for (int i = 0; i < 16; ++i) f[i] = src[i];
        half8* X16 = reinterpret_cast<half8*>(smem);
#pragma unroll
        for (int j = 0; j < 8; ++j) {
            float4 A = f[2 * j], B = f[2 * j + 1];
            half8 h;
            h[0] = (_Float16)A.x; h[1] = (_Float16)A.y; h[2] = (_Float16)A.z; h[3] = (_Float16)A.w;
            h[4] = (_Float16)B.x; h[5] = (_Float16)B.y; h[6] = (_Float16)B.z; h[7] = (_Float16)B.w;
            X16[(qd * 8 + j) * 64 + row] = h;   // [kq 0..31][row 0..63]
        }
    }
    __syncthreads();

    const half8* X16 = reinterpret_cast<const half8*>(smem);
    const half8* epv = reinterpret_cast<const half8*>(ep);

    float t1[4], t2[4]; int i1[4], i2[4];
#pragma unroll
    for (int r = 0; r < 4; ++r) { t1[r] = -3.0e38f; t2[r] = -3.0e38f; i1[r] = 0; i2[r] = 0; }

    for (int o = 0; o < 4; ++o) {
        // E 16B-slot for (ks, cfr): w*8192 + ks*1024 + lq*256 + o*64 + cfr*16 + l15
        const int eb = w * 8192 + lq * 256 + o * 64 + l15;

        floatx4 acc[4][4];   // [cfr][rf]
#pragma unroll
        for (int cfr = 0; cfr < 4; ++cfr)
#pragma unroll
            for (int rf = 0; rf < 4; ++rf)
                acc[cfr][rf] = (floatx4){0.f, 0.f, 0.f, 0.f};

        half8 eF[2][4];      // depth-2 k-step ring, parity index static
#pragma unroll
        for (int cfr = 0; cfr < 4; ++cfr)
            eF[0][cfr] = epv[eb + cfr * 16];

#pragma unroll
        for (int ks = 0; ks < 8; ++ks) {
            if (ks < 7) {
#pragma unroll
                for (int cfr = 0; cfr < 4; ++cfr)
                    eF[(ks + 1) & 1][cfr] = epv[eb + (ks + 1) * 1024 + cfr * 16];
            }
            half8 xf[4];
#pragma unroll
            for (int rf = 0; rf < 4; ++rf)
                xf[rf] = X16[(ks * 4 + lq) * 64 + rf * 16 + l15];

            __builtin_amdgcn_s_setprio(1);
#pragma unroll
            for (int cfr = 0; cfr < 4; ++cfr)
#pragma unroll
                for (int rf = 0; rf < 4; ++rf)
                    acc[cfr][rf] = __builtin_amdgcn_mfma_f32_16x16x32_f16(
                        eF[ks & 1][cfr], xf[rf], acc[cfr][rf], 0, 0, 0);
            __builtin_amdgcn_s_setprio(0);
        }

        // ---- epilogue o: q = dot - cnorm/2, per-lane top-2 per row-frag ----
#pragma unroll
        for (int cfr = 0; cfr < 4; ++cfr) {
            const int cb0 = w * 256 + o * 64 + cfr * 16 + lq * 4;
            float4 cn = *reinterpret_cast<const float4*>(cnorm + cb0);
            float cnl[4] = {cn.x, cn.y, cn.z, cn.w};
#pragma unroll
            for (int reg = 0; reg < 4; ++reg) {
                const int code = cb0 + reg;
#pragma unroll
                for (int rf = 0; rf < 4; ++rf) {
                    float q = acc[cfr][rf][reg] - 0.5f * cnl[reg];
                    bool b1 = q > t1[rf], b2 = q > t2[rf];
                    t2[rf] = b1 ? t1[rf] : (b2 ? q : t2[rf]);
                    i2[rf] = b1 ? i1[rf] : (b2 ? code : i2[rf]);
                    t1[rf] = b1 ? q    : t1[rf];
                    i1[rf] = b1 ? code : i1[rf];
                }
            }
        }
    }

    // ---- dump candidates: [64 rows][32 slots] (reuses X LDS) ----
    __syncthreads();   // all waves done reading X
    float* candV = reinterpret_cast<float*>(smem);           // 8 KB
    int*   candI = reinterpret_cast<int*>(smem + 8192);      // 8 KB
    int*   bmu   = reinterpret_cast<int*>(smem + 16384);
#pragma unroll
    for (int rf = 0; rf < 4; ++rf) {
        int r = rf * 16 + l15;
        int base = r * 32 + (w * 4 + lq) * 2;
        candV[base]     = t1[rf]; candI[base]     = i1[rf];
        candV[base + 1] = t2[rf]; candI[base + 1] = i2[rf];
    }
    __syncthreads();

    // ---- per-row decision: margin fast path or exact refine (validated) ----
    const float THR = 1.0e-2f;
    for (int p = 0; p < 8; ++p) {
        int r = p * 8 + w * 2 + (lane >> 5);
        int j = lane & 31;
        float v  = candV[r * 32 + j];
        int   id = candI[r * 32 + j];

        float V1 = v, V2 = -3.0e38f; int I1 = id, I2 = 0;
#pragma unroll
        for (int m = 1; m < 32; m <<= 1) {
            float pv1 = __shfl_xor(V1, m, 64); int pi1 = __shfl_xor(I1, m, 64);
            float pv2 = __shfl_xor(V2, m, 64); int pi2 = __shfl_xor(I2, m, 64);
            bool sw = pv1 > V1;
            float w1 = sw ? pv1 : V1; int wi1 = sw ? pi1 : I1;
            float lo = sw ? V1 : pv1; int loi = sw ? I1 : pi1;
            float s2 = sw ? pv2 : V2; int s2i = sw ? pi2 : I2;
            bool g = lo > s2;
            V1 = w1; I1 = wi1;
            V2 = g ? lo : s2; I2 = g ? loi : s2i;
        }

        int chosen;
        if (2.0f * (V1 - V2) >= THR) {
            chosen = I1;
        } else {
            const float* xr = x + (size_t)(row0 + r) * DDIM;
            const float* cr = cb + (size_t)id * DDIM;
            double m = 0.0;
            for (int d = 0; d < DDIM; ++d)
                m = fma((double)xr[d], (double)cr[d], m);
            float M  = (float)m;
            float xn = xnorm_np_g(xr);
            float s  = __fsub_rn(__fadd_rn(xn, cnorm[id]), __fmul_rn(2.0f, M));
#pragma unroll
            for (int m2 = 1; m2 < 32; m2 <<= 1) {
                float ps = __shfl_xor(s, m2, 64); int pid = __shfl_xor(id, m2, 64);
                bool take = (ps < s) || (ps == s && pid < id);
                s  = take ? ps  : s;
                id = take ? pid : id;
            }
            chosen = id;
        }
        if (j == 0) bmu[r] = chosen;
    }
    __syncthreads();

    // ---- gather: out[row] = codebook[bmu[row]] ----
    float4* out4 = reinterpret_cast<float4*>(out);
    const float4* cb4 = reinterpret_cast<const float4*>(cb);
#pragma unroll
    for (int p = 0; p < 16; ++p) {
        int idx = p * 256 + tid;
        int r = idx >> 6, sl = idx & 63;
        int code = bmu[r];
        out4[(size_t)(row0 + r) * 64 + sl] = cb4[(size_t)code * 64 + sl];
    }
}

extern "C" void kernel_launch(void* const* d_in, const int* in_sizes, int n_in,
                              void* d_out, int out_size, void* d_ws, size_t ws_size,
                              hipStream_t stream) {
    const float* x  = (const float*)d_in[0];
    const float* cb = (const float*)d_in[1];
    float* out = (float*)d_out;

    float*    cnorm = (float*)d_ws;
    _Float16* ep    = (_Float16*)((char*)d_ws + 4096);

    prep_kernel<<<dim3(64), dim3(512), 0, stream>>>(cb, cnorm, ep);
    som_mfma_kernel<<<dim3(512), dim3(256), 0, stream>>>(x, cb, cnorm, ep, out);
}

// Round 9
// 62.703 us; speedup vs baseline: 1.4181x; 1.4181x over previous
//
#include <hip/hip_runtime.h>

#define NROWS  32768
#define DDIM   256
#define KCODES 1024

typedef _Float16 half8 __attribute__((ext_vector_type(8)));
typedef float floatx4 __attribute__((ext_vector_type(4)));
typedef __attribute__((address_space(3))) void lds_void;
typedef __attribute__((address_space(1))) const void glb_cvoid;

// ws layout: [0,4096) f32 cnorm[1024];
//            [4096, 4096+524288) fp16 E' chunk-major fragment-ready:
//   chunk t = o*8+kc (o: 256-code tile, kc: 32-depth slice), 16 KB each.
//   16B slot within chunk = lq*256 + c_rel  holds fp16 of
//   cb[o*256+c_rel][kc*32 + lq*8 .. +8)

// ---------------------------------------------------------------------------
// prep kernel: codebook f32 -> fp16 fragment layout + np-pairwise cnorm
// (validated R1-R8, unchanged)
// ---------------------------------------------------------------------------
__global__ void prep_kernel(const float* __restrict__ cb,
                            float* __restrict__ cnorm,
                            _Float16* __restrict__ ep) {
    int idx  = blockIdx.x * 512 + threadIdx.x;   // 64 x 512 = 32768
    int code = idx >> 5, kl = idx & 31;
    int dc = kl >> 2, lq = kl & 3;
    int ct = code >> 8, cr = code & 255;
    const float4* s = reinterpret_cast<const float4*>(cb + (size_t)code * DDIM + kl * 8);
    float4 a = s[0], b = s[1];
    half8 h;
    h[0] = (_Float16)a.x; h[1] = (_Float16)a.y; h[2] = (_Float16)a.z; h[3] = (_Float16)a.w;
    h[4] = (_Float16)b.x; h[5] = (_Float16)b.y; h[6] = (_Float16)b.z; h[7] = (_Float16)b.w;
    size_t slot = (size_t)(ct * 8 + dc) * 1024 + lq * 256 + cr;
    *reinterpret_cast<half8*>(ep + slot * 8) = h;

    if (threadIdx.x < 16) {
        int k = blockIdx.x * 16 + threadIdx.x;
        const float* p = cb + (size_t)k * DDIM;
        float halves[2];
        for (int hh = 0; hh < 2; ++hh) {
            const float* aa = p + hh * 128;
            float r[8];
#pragma unroll
            for (int j = 0; j < 8; ++j) r[j] = __fmul_rn(aa[j], aa[j]);
            for (int i = 8; i < 128; i += 8) {
#pragma unroll
                for (int j = 0; j < 8; ++j)
                    r[j] = __fadd_rn(r[j], __fmul_rn(aa[i + j], aa[i + j]));
            }
            halves[hh] = __fadd_rn(__fadd_rn(__fadd_rn(r[0], r[1]), __fadd_rn(r[2], r[3])),
                                   __fadd_rn(__fadd_rn(r[4], r[5]), __fadd_rn(r[6], r[7])));
        }
        cnorm[k] = __fadd_rn(halves[0], halves[1]);
    }
}

// numpy-pairwise ||x||^2 from a global row pointer (validated R2-R8)
__device__ __forceinline__ float xnorm_np_g(const float* __restrict__ p) {
    float halves[2];
    for (int h = 0; h < 2; ++h) {
        const float* a = p + h * 128;
        float r[8];
#pragma unroll
        for (int j = 0; j < 8; ++j) r[j] = __fmul_rn(a[j], a[j]);
        for (int i = 8; i < 128; i += 8) {
#pragma unroll
            for (int j = 0; j < 8; ++j)
                r[j] = __fadd_rn(r[j], __fmul_rn(a[i + j], a[i + j]));
        }
        halves[h] = __fadd_rn(__fadd_rn(__fadd_rn(r[0], r[1]), __fadd_rn(r[2], r[3])),
                              __fadd_rn(__fadd_rn(r[4], r[5]), __fadd_rn(r[6], r[7])));
    }
    return __fadd_rn(halves[0], halves[1]);
}

// issue 4 global_load_lds (16 KB chunk staged by 4 waves, 4 KB each)
#define STAGE(T, BUF)                                                          \
    {                                                                          \
        const char* gsrc = epc + (size_t)(T) * 16384 + w * 4096 + (lane << 4); \
        char* ldst = (BUF) + w * 4096;                                         \
        __builtin_amdgcn_global_load_lds((glb_cvoid*)(gsrc),        (lds_void*)(ldst),        16, 0, 0); \
        __builtin_amdgcn_global_load_lds((glb_cvoid*)(gsrc + 1024), (lds_void*)(ldst + 1024), 16, 0, 0); \
        __builtin_amdgcn_global_load_lds((glb_cvoid*)(gsrc + 2048), (lds_void*)(ldst + 2048), 16, 0, 0); \
        __builtin_amdgcn_global_load_lds((glb_cvoid*)(gsrc + 3072), (lds_void*)(ldst + 3072), 16, 0, 0); \
    }

// ---------------------------------------------------------------------------
// main kernel: 64 rows/block, 4 waves x 64-code strips per 256-code tile.
// E' in a 3-deep LDS ring fed by global_load_lds, staged 2 chunks ahead,
// counted vmcnt (never 0 in steady state), raw s_barrier + sched_barrier.
// Per chunk per wave: 8 ds_read_b128 + 16 MFMA. acc 64 VGPR (~130 total).
// Top-2 + margin fast path + exact refine + gather validated R2-R8.
// ---------------------------------------------------------------------------
__global__ __launch_bounds__(256, 2) void som_mfma_kernel(
    const float* __restrict__ x, const float* __restrict__ cb,
    const float* __restrict__ cnorm, const _Float16* __restrict__ ep,
    float* __restrict__ out)
{
    __shared__ __align__(16) char smem[81920];   // X 32K | E ring 3x16K
    char* ering = smem + 32768;

    const int tid  = threadIdx.x;
    const int lane = tid & 63, w = tid >> 6;     // wave 0..3
    const int l15  = lane & 15, lq = lane >> 4;
    const int row0 = blockIdx.x * 64;
    const char* epc = (const char*)ep;

    // ---- stage X (64 rows) coalesced -> fp16 fragment layout in LDS ----
    {
        int row = tid >> 2, qd = tid & 3;
        const float4* src = reinterpret_cast<const float4*>(
            x + (size_t)(row0 + row) * DDIM + qd * 64);
        float4 f[16];
#pragma unroll
        for (int i = 0; i < 16; ++i) f[i] = src[i];
        half8* X16w = reinterpret_cast<half8*>(smem);
#pragma unroll
        for (int j = 0; j < 8; ++j) {
            float4 A = f[2 * j], B = f[2 * j + 1];
            half8 h;
            h[0] = (_Float16)A.x; h[1] = (_Float16)A.y; h[2] = (_Float16)A.z; h[3] = (_Float16)A.w;
            h[4] = (_Float16)B.x; h[5] = (_Float16)B.y; h[6] = (_Float16)B.z; h[7] = (_Float16)B.w;
            X16w[(qd * 8 + j) * 64 + row] = h;   // [kq 0..31][row 0..63]
        }
    }

    // ---- prologue: stage chunks 0,1 into ring bufs 0,1 ----
    STAGE(0, ering)
    STAGE(1, ering + 16384)
    __syncthreads();   // full drain once: X + chunks 0,1 resident; queue empty

    const half8* X16 = reinterpret_cast<const half8*>(smem);

    float t1[4], t2[4]; int i1[4], i2[4];
#pragma unroll
    for (int r = 0; r < 4; ++r) { t1[r] = -3.0e38f; t2[r] = -3.0e38f; i1[r] = 0; i2[r] = 0; }

#pragma unroll
    for (int o = 0; o < 4; ++o) {
        floatx4 acc[4][4];   // [cfr][rf]
#pragma unroll
        for (int cfr = 0; cfr < 4; ++cfr)
#pragma unroll
            for (int rf = 0; rf < 4; ++rf)
                acc[cfr][rf] = (floatx4){0.f, 0.f, 0.f, 0.f};

        float4 cn4[4];

#pragma unroll
        for (int kc = 0; kc < 8; ++kc) {
            const int t = o * 8 + kc;

            // counted wait: my stage(t) retired. queue at entry:
            //   kc<7      : [t(4), t+1(4)]            -> vmcnt(4)
            //   kc==7,o<3 : [t(4), cn(4), t+1(4)]     -> vmcnt(8)
            //   kc==7,o==3: [t(4), cn(4)]             -> vmcnt(4)
            if (kc == 7) {
                if (o == 3) asm volatile("s_waitcnt vmcnt(4)" ::: "memory");
                else        asm volatile("s_waitcnt vmcnt(8)" ::: "memory");
            } else {
                asm volatile("s_waitcnt vmcnt(4)" ::: "memory");
            }
            __builtin_amdgcn_s_barrier();          // chunk t certified in LDS
            __builtin_amdgcn_sched_barrier(0);     // no motion across barrier

            if (kc == 6) {   // prefetch cnorm for this o (before stage issue)
#pragma unroll
                for (int cfr = 0; cfr < 4; ++cfr)
                    cn4[cfr] = *reinterpret_cast<const float4*>(
                        cnorm + o * 256 + w * 64 + cfr * 16 + lq * 4);
            }
            if (t + 2 < 32) {                      // stage 2 ahead into freed buf
                char* nbuf = ering + ((t + 2) % 3) * 16384;
                STAGE(t + 2, nbuf)
            }

            const half8* Ev = reinterpret_cast<const half8*>(ering + (t % 3) * 16384);
            half8 xf[4];
#pragma unroll
            for (int rf = 0; rf < 4; ++rf)
                xf[rf] = X16[(kc * 4 + lq) * 64 + rf * 16 + l15];

            __builtin_amdgcn_s_setprio(1);
#pragma unroll
            for (int cfr = 0; cfr < 4; ++cfr) {
                half8 e = Ev[lq * 256 + w * 64 + cfr * 16 + l15];
#pragma unroll
                for (int rf = 0; rf < 4; ++rf)
                    acc[cfr][rf] = __builtin_amdgcn_mfma_f32_16x16x32_f16(
                        e, xf[rf], acc[cfr][rf], 0, 0, 0);
            }
            __builtin_amdgcn_s_setprio(0);
        }

        // ---- epilogue o: q = dot - cnorm/2, per-lane top-2 per row-frag ----
#pragma unroll
        for (int cfr = 0; cfr < 4; ++cfr) {
            const int cb0 = o * 256 + w * 64 + cfr * 16 + lq * 4;
            float cnl[4] = {cn4[cfr].x, cn4[cfr].y, cn4[cfr].z, cn4[cfr].w};
#pragma unroll
            for (int reg = 0; reg < 4; ++reg) {
                const int code = cb0 + reg;
#pragma unroll
                for (int rf = 0; rf < 4; ++rf) {
                    float q = acc[cfr][rf][reg] - 0.5f * cnl[reg];
                    bool b1 = q > t1[rf], b2 = q > t2[rf];
                    t2[rf] = b1 ? t1[rf] : (b2 ? q : t2[rf]);
                    i2[rf] = b1 ? i1[rf] : (b2 ? code : i2[rf]);
                    t1[rf] = b1 ? q    : t1[rf];
                    i1[rf] = b1 ? code : i1[rf];
                }
            }
        }
    }

    // ---- dump candidates: [64 rows][32 slots] (reuses X LDS) ----
    __syncthreads();   // full drain: all waves done with X and E ring
    float* candV = reinterpret_cast<float*>(smem);           // 8 KB
    int*   candI = reinterpret_cast<int*>(smem + 8192);      // 8 KB
    int*   bmu   = reinterpret_cast<int*>(smem + 16384);
#pragma unroll
    for (int rf = 0; rf < 4; ++rf) {
        int r = rf * 16 + l15;
        int base = r * 32 + (w * 4 + lq) * 2;
        candV[base]     = t1[rf]; candI[base]     = i1[rf];
        candV[base + 1] = t2[rf]; candI[base + 1] = i2[rf];
    }
    __syncthreads();

    // ---- per-row decision: margin fast path or exact refine (validated) ----
    const float THR = 1.0e-2f;
    for (int p = 0; p < 8; ++p) {
        int r = p * 8 + w * 2 + (lane >> 5);
        int j = lane & 31;
        float v  = candV[r * 32 + j];
        int   id = candI[r * 32 + j];

        float V1 = v, V2 = -3.0e38f; int I1 = id, I2 = 0;
#pragma unroll
        for (int m = 1; m < 32; m <<= 1) {
            float pv1 = __shfl_xor(V1, m, 64); int pi1 = __shfl_xor(I1, m, 64);
            float pv2 = __shfl_xor(V2, m, 64); int pi2 = __shfl_xor(I2, m, 64);
            bool sw = pv1 > V1;
            float w1 = sw ? pv1 : V1; int wi1 = sw ? pi1 : I1;
            float lo = sw ? V1 : pv1; int loi = sw ? I1 : pi1;
            float s2 = sw ? pv2 : V2; int s2i = sw ? pi2 : I2;
            bool g = lo > s2;
            V1 = w1; I1 = wi1;
            V2 = g ? lo : s2; I2 = g ? loi : s2i;
        }

        int chosen;
        if (2.0f * (V1 - V2) >= THR) {
            chosen = I1;
        } else {
            const float* xr = x + (size_t)(row0 + r) * DDIM;
            const float* cr = cb + (size_t)id * DDIM;
            double m = 0.0;
            for (int d = 0; d < DDIM; ++d)
                m = fma((double)xr[d], (double)cr[d], m);
            float M  = (float)m;
            float xn = xnorm_np_g(xr);
            float s  = __fsub_rn(__fadd_rn(xn, cnorm[id]), __fmul_rn(2.0f, M));
#pragma unroll
            for (int m2 = 1; m2 < 32; m2 <<= 1) {
                float ps = __shfl_xor(s, m2, 64); int pid = __shfl_xor(id, m2, 64);
                bool take = (ps < s) || (ps == s && pid < id);
                s  = take ? ps  : s;
                id = take ? pid : id;
            }
            chosen = id;
        }
        if (j == 0) bmu[r] = chosen;
    }
    __syncthreads();

    // ---- gather: out[row] = codebook[bmu[row]] ----
    float4* out4 = reinterpret_cast<float4*>(out);
    const float4* cb4 = reinterpret_cast<const float4*>(cb);
#pragma unroll
    for (int p = 0; p < 16; ++p) {
        int idx = p * 256 + tid;
        int r = idx >> 6, sl = idx & 63;
        int code = bmu[r];
        out4[(size_t)(row0 + r) * 64 + sl] = cb4[(size_t)code * 64 + sl];
    }
}

extern "C" void kernel_launch(void* const* d_in, const int* in_sizes, int n_in,
                              void* d_out, int out_size, void* d_ws, size_t ws_size,
                              hipStream_t stream) {
    const float* x  = (const float*)d_in[0];
    const float* cb = (const float*)d_in[1];
    float* out = (float*)d_out;

    float*    cnorm = (float*)d_ws;
    _Float16* ep    = (_Float16*)((char*)d_ws + 4096);

    prep_kernel<<<dim3(64), dim3(512), 0, stream>>>(cb, cnorm, ep);
    som_mfma_kernel<<<dim3(512), dim3(256), 0, stream>>>(x, cb, cnorm, ep, out);
}